// Round 11
// baseline (287.863 us; speedup 1.0000x reference)
//
#include <hip/hip_runtime.h>
#include <math.h>

#define NEMB 256
#define DIM 64
#define SIGS_B 64                 // signals per block
#define THREADS 256               // 4 waves per block
#define NSIG 131072
#define GRID (NSIG / SIGS_B)      // 2048

#define LOG1P50 3.9318256327243257        // np.log1p(50.0), f64
#define INV_MU_F ((float)(1.0 / LOG1P50)) // fp32-rounded scalar, as numpy uses
#define TWO15_F ((float)(2.0 / 15.0))

// dynamic LDS layout (byte offsets) — Dn NOT staged (L2-hot from global)
#define LB_SIG   0          // 16384 B : sig f32 [c][w]  (64 x 64)
#define LB_XS    16384      // 1024 B  : raw coeffs f32 [4][SIGS_B]
#define LB_QI    17408      // 1024 B  : qi i32 [4][SIGS_B]
#define LB_RED   18432      // 32 B    : per-wave loss partials (f64)
#define LDS_BYTES 18464

typedef float f2 __attribute__((ext_vector_type(2)));

__device__ __forceinline__ float rdlane_f(float v, int lane)
{
    return __builtin_bit_cast(float, __builtin_amdgcn_readlane(__builtin_bit_cast(int, v), lane));
}

template<int CTRL>
__device__ __forceinline__ float dpp_fmax(float m)
{
    int sh = __builtin_amdgcn_update_dpp(0, __builtin_bit_cast(int, m), CTRL, 0xf, 0xf, true);
    return fmaxf(m, __builtin_bit_cast(float, sh));
}

// wave-wide max of non-negative values; valid in lane 63. Pure VALU (DPP).
__device__ __forceinline__ float wave_max_nn(float v)
{
    v = dpp_fmax<0x111>(v);   // row_shr:1
    v = dpp_fmax<0x112>(v);   // row_shr:2
    v = dpp_fmax<0x114>(v);   // row_shr:4
    v = dpp_fmax<0x118>(v);   // row_shr:8  -> lane 15/31/47/63 = row max
    v = dpp_fmax<0x142>(v);   // row_bcast:15 -> lane 31/63 = half max
    v = dpp_fmax<0x143>(v);   // row_bcast:31 -> lane 63 = wave max
    return v;
}

// Fused normalize + gram (+ DnT transpose for the store-phase vector gathers).
__global__ void k_ng(const float* __restrict__ D, float* __restrict__ Dn,
                     float* __restrict__ DnT, float* __restrict__ G,
                     double* __restrict__ loss_acc, unsigned int* __restrict__ ctr)
{
#pragma clang fp contract(off)
    __shared__ float nrmS[NEMB];
    __shared__ float coli[DIM];
    int i = blockIdx.x, j = threadIdx.x;
    if (i == 0 && j == 0) { loss_acc[0] = 0.0; ctr[0] = 0u; }
    float ss = 0.0f;
    for (int c = 0; c < DIM; c++) {
        float v = D[c * NEMB + j];
        float sq = v * v;
        ss = ss + sq;
    }
    float nrm = fmaxf(sqrtf(ss), 1e-10f);
    nrmS[j] = nrm;
    __syncthreads();
    if (j < DIM) {
        float dni = D[j * NEMB + i] / nrmS[i];
        coli[j] = dni;
        Dn[j * NEMB + i] = dni;         // block i owns Dn column i
        DnT[i * DIM + j] = dni;         // and DnT row i (same bits)
    }
    __syncthreads();
    float s = 0.0f;
#pragma unroll 8
    for (int c = 0; c < DIM; c++) {
        float dnj = D[c * NEMB + j] / nrm;     // rounds identically to Dn[c][j]
        s = fmaf(coli[c], dnj, s);
    }
    G[i * NEMB + j] = s;
}

// mu-law quantize+decode, all fp32, numpy op-for-op (no fusion)
__device__ __forceinline__ float quant_decode(float coeff)
{
#pragma clang fp contract(off)
    float c = fminf(fmaxf(coeff, -3.0f), 3.0f) / 3.0f;
    float ac = fabsf(c);
    float sgn = (c > 0.0f) ? 1.0f : ((c < 0.0f) ? -1.0f : 0.0f);
    float l = log1pf(ac * 50.0f);
    float enc = (sgn * l) * INV_MU_F;
    float scaled = (enc + 1.0f) * 7.5f;
    int bin = (int)rintf(scaled);              // round-half-even == np.round
    bin = bin < 0 ? 0 : (bin > 15 ? 15 : bin);
    float t = (float)bin * TWO15_F;
    float zv = t - 1.0f;
    float az = fabsf(zv);
    float sz = (zv > 0.0f) ? 1.0f : ((zv < 0.0f) ? -1.0f : 0.0f);
    float e = expm1f(az / INV_MU_F);
    return (sz * (e / 50.0f)) * 3.0f;
}

// FOUR signals' OMP (K=4) per call, fully scalarized. R11 change vs R10:
// shrink the G-row register cache from 3 rows to ONE (row 0 only, 6 uses).
// Rows 1/2 are consumed as freshly-loaded temps (row 1 reloaded once at
// kk=2, L1/L2-hot, issued before chol -> hidden); Gs1/Gs2 at kk=3 are
// direct scalar loads (R7-proven pattern). Same G elements, same fp op
// order -> bit-identical results. Support indices packed into one int.
// Purpose: VGPR 112 -> ~80 => occupancy tier 4 -> 5-6 waves/SIMD.
__device__ __forceinline__ void omp_quad4(
    f2 sA0, f2 sA1, f2 sB0, f2 sB1, f2 sC0, f2 sC1, f2 sD0, f2 sD1,
    int lane, int qt,
    const float* __restrict__ G,
    float* __restrict__ xsv, int* __restrict__ qi, int s0)
{
#pragma clang fp contract(off)
    f2 hA0 = sA0, hA1 = sA1, hB0 = sB0, hB1 = sB1;
    f2 hC0 = sC0, hC1 = sC1, hD0 = sD0, hD1 = sD1;
    int m4A = 0, m4B = 0, m4C = 0, m4D = 0;
    f2 gA00, gA01;                 // cached G row 0 (the only persisted row)
    f2 gB00, gB01;
    f2 gC00, gC01;
    f2 gD00, gD01;
    int iqp = 0;                   // packed support indices, 8 bits each
    float L10, L11, L20, L21, L22, L30, L31, L32, L33;
    float y0, y1, y2, y3;
    float x0 = 0.f, x1 = 0.f, x2 = 0.f, x3 = 0.f;
#pragma unroll
    for (int kk = 0; kk < 4; kk++) {
        // ---- per-lane best of own 4 atoms (ascending j, strict >) x4 ----
        float aA0 = (m4A & 1) ? 0.f : fabsf(hA0[0]);
        float aA1 = (m4A & 2) ? 0.f : fabsf(hA0[1]);
        float aA2 = (m4A & 4) ? 0.f : fabsf(hA1[0]);
        float aA3 = (m4A & 8) ? 0.f : fabsf(hA1[1]);
        float bvA = aA0; int bjA = 0;
        if (aA1 > bvA) { bvA = aA1; bjA = 1; }
        if (aA2 > bvA) { bvA = aA2; bjA = 2; }
        if (aA3 > bvA) { bvA = aA3; bjA = 3; }
        float aB0 = (m4B & 1) ? 0.f : fabsf(hB0[0]);
        float aB1 = (m4B & 2) ? 0.f : fabsf(hB0[1]);
        float aB2 = (m4B & 4) ? 0.f : fabsf(hB1[0]);
        float aB3 = (m4B & 8) ? 0.f : fabsf(hB1[1]);
        float bvB = aB0; int bjB = 0;
        if (aB1 > bvB) { bvB = aB1; bjB = 1; }
        if (aB2 > bvB) { bvB = aB2; bjB = 2; }
        if (aB3 > bvB) { bvB = aB3; bjB = 3; }
        float aC0 = (m4C & 1) ? 0.f : fabsf(hC0[0]);
        float aC1 = (m4C & 2) ? 0.f : fabsf(hC0[1]);
        float aC2 = (m4C & 4) ? 0.f : fabsf(hC1[0]);
        float aC3 = (m4C & 8) ? 0.f : fabsf(hC1[1]);
        float bvC = aC0; int bjC = 0;
        if (aC1 > bvC) { bvC = aC1; bjC = 1; }
        if (aC2 > bvC) { bvC = aC2; bjC = 2; }
        if (aC3 > bvC) { bvC = aC3; bjC = 3; }
        float aD0 = (m4D & 1) ? 0.f : fabsf(hD0[0]);
        float aD1 = (m4D & 2) ? 0.f : fabsf(hD0[1]);
        float aD2 = (m4D & 4) ? 0.f : fabsf(hD1[0]);
        float aD3 = (m4D & 8) ? 0.f : fabsf(hD1[1]);
        float bvD = aD0; int bjD = 0;
        if (aD1 > bvD) { bvD = aD1; bjD = 1; }
        if (aD2 > bvD) { bvD = aD2; bjD = 2; }
        if (aD3 > bvD) { bvD = aD3; bjD = 3; }
        // ---- wave max (value only) x4, then first-lane tie-break ----
        float rA = wave_max_nn(bvA);
        float rB = wave_max_nn(bvB);
        float rC = wave_max_nn(bvC);
        float rD = wave_max_nn(bvD);
        float vmA = rdlane_f(rA, 63), vmB = rdlane_f(rB, 63);
        float vmC = rdlane_f(rC, 63), vmD = rdlane_f(rD, 63);
        unsigned long long blA = __ballot(bvA == vmA);
        unsigned long long blB = __ballot(bvB == vmB);
        unsigned long long blC = __ballot(bvC == vmC);
        unsigned long long blD = __ballot(bvD == vmD);
        int owA = __ffsll((long long)blA) - 1;
        int owB = __ffsll((long long)blB) - 1;
        int owC = __ffsll((long long)blC) - 1;
        int owD = __ffsll((long long)blD) - 1;
        int boA = __builtin_amdgcn_readlane(bjA, owA);
        int boB = __builtin_amdgcn_readlane(bjB, owB);
        int boC = __builtin_amdgcn_readlane(bjC, owC);
        int boD = __builtin_amdgcn_readlane(bjD, owD);
        int idA = 4 * owA + boA;       // uniform
        int idB = 4 * owB + boB;
        int idC = 4 * owC + boC;
        int idD = 4 * owD + boD;
        m4A |= (lane == owA) ? (1 << boA) : 0;
        m4B |= (lane == owB) ? (1 << boB) : 0;
        m4C |= (lane == owC) ? (1 << boC) : 0;
        m4D |= (lane == owD) ? (1 << boD) : 0;
        // ---- original h_bar at selected atom ----
        float tvA = sA0[0];
        tvA = (bjA == 1) ? sA0[1] : tvA;
        tvA = (bjA == 2) ? sA1[0] : tvA;
        tvA = (bjA == 3) ? sA1[1] : tvA;
        float tvB = sB0[0];
        tvB = (bjB == 1) ? sB0[1] : tvB;
        tvB = (bjB == 2) ? sB1[0] : tvB;
        tvB = (bjB == 3) ? sB1[1] : tvB;
        float tvC = sC0[0];
        tvC = (bjC == 1) ? sC0[1] : tvC;
        tvC = (bjC == 2) ? sC1[0] : tvC;
        tvC = (bjC == 3) ? sC1[1] : tvC;
        float tvD = sD0[0];
        tvD = (bjD == 1) ? sD0[1] : tvD;
        tvD = (bjD == 2) ? sD1[0] : tvD;
        tvD = (bjD == 3) ? sD1[1] : tvD;
        float hsA = rdlane_f(tvA, owA);
        float hsB = rdlane_f(tvB, owB);
        float hsC = rdlane_f(tvC, owC);
        float hsD = rdlane_f(tvD, owD);
        float hsel = (qt & 2) ? ((qt & 1) ? hsD : hsC) : ((qt & 1) ? hsB : hsA);
        int idxq = (qt & 2) ? ((qt & 1) ? idD : idC) : ((qt & 1) ? idB : idA);
        iqp |= idxq << (8 * kk);
        // ---- this kk's row loads (issued early; hidden under chol/solves) ----
        const int l4 = 4 * lane;
        float4 r1A, r1B, r1C, r1D;     // row kk=1 temps (kk==1: fresh; kk==2: reload)
        float4 r2A, r2B, r2C, r2D;     // row kk=2 temps (kk==2 only)
        if (kk == 0) {
            float4 ra = *(const float4*)(G + ((size_t)idA << 8) + l4);
            float4 rb = *(const float4*)(G + ((size_t)idB << 8) + l4);
            float4 rc = *(const float4*)(G + ((size_t)idC << 8) + l4);
            float4 rd = *(const float4*)(G + ((size_t)idD << 8) + l4);
            gA00 = (f2){ra.x, ra.y}; gA01 = (f2){ra.z, ra.w};
            gB00 = (f2){rb.x, rb.y}; gB01 = (f2){rb.z, rb.w};
            gC00 = (f2){rc.x, rc.y}; gC01 = (f2){rc.z, rc.w};
            gD00 = (f2){rd.x, rd.y}; gD01 = (f2){rd.z, rd.w};
        }
        if (kk == 1) {
            r1A = *(const float4*)(G + ((size_t)idA << 8) + l4);
            r1B = *(const float4*)(G + ((size_t)idB << 8) + l4);
            r1C = *(const float4*)(G + ((size_t)idC << 8) + l4);
            r1D = *(const float4*)(G + ((size_t)idD << 8) + l4);
        }
        int id1A = 0, id1B = 0, id1C = 0, id1D = 0;
        if (kk == 2) {
            // reload row 1 (per-signal kk=1 atom rows; need uniform per signal)
            // NOTE: row-1 indices are the kk=1 selections; recover from iqp of
            // each signal? iqp is per-lane (own quarter). The row-1 index per
            // SIGNAL is uniform: it was idA/idB/idC/idD at kk==1. Persist them.
            // (handled via id1X variables set below at kk==1 — see loop tail)
        }
        // persist kk==1 selections for the kk==2 reload (uniform scalars)
        // -- implemented by shadow variables outside the unrolled iteration:
        //    we use iqp unpacking instead: signal-m's row-1 index is only
        //    known per-quarter in iqp. So persist the four uniform ids:
        static_assert(true, "");
        // (see id1s below)
        (void)id1A; (void)id1B; (void)id1C; (void)id1D;
        // ---- Gs values for chol ----
        float Gs0 = 0.f, Gs1 = 0.f, Gs2 = 0.f;
        if (kk > 0) {
            float eA = gA00[0];
            eA = (boA == 1) ? gA00[1] : eA;
            eA = (boA == 2) ? gA01[0] : eA;
            eA = (boA == 3) ? gA01[1] : eA;
            float eB = gB00[0];
            eB = (boB == 1) ? gB00[1] : eB;
            eB = (boB == 2) ? gB01[0] : eB;
            eB = (boB == 3) ? gB01[1] : eB;
            float eC = gC00[0];
            eC = (boC == 1) ? gC00[1] : eC;
            eC = (boC == 2) ? gC01[0] : eC;
            eC = (boC == 3) ? gC01[1] : eC;
            float eD = gD00[0];
            eD = (boD == 1) ? gD00[1] : eD;
            eD = (boD == 2) ? gD01[0] : eD;
            eD = (boD == 3) ? gD01[1] : eD;
            float GsA = rdlane_f(eA, owA);
            float GsB = rdlane_f(eB, owB);
            float GsC = rdlane_f(eC, owC);
            float GsD = rdlane_f(eD, owD);
            Gs0 = (qt & 2) ? ((qt & 1) ? GsD : GsC) : ((qt & 1) ? GsB : GsA);
        }
        if (kk == 2 || kk == 3) {
            // Gs1 = G[iq1][idx_new]: direct load (quarter-uniform addr, L1-hot)
            int iq1v = (iqp >> 8) & 255;
            Gs1 = G[((size_t)iq1v << 8) + idxq];
        }
        if (kk == 3) {
            int iq2v = (iqp >> 16) & 255;
            Gs2 = G[((size_t)iq2v << 8) + idxq];
        }
        if (kk == 2) {
            // reload row 1 for the residual: per-signal uniform index = the
            // kk=1 selection. Recover per signal from each quarter's iqp via
            // readlane of quarter-lead lanes (0,16,32,48) — SGPR, uniform.
            int iqA1 = (__builtin_amdgcn_readlane(iqp, 0)  >> 8) & 255;
            int iqB1 = (__builtin_amdgcn_readlane(iqp, 16) >> 8) & 255;
            int iqC1 = (__builtin_amdgcn_readlane(iqp, 32) >> 8) & 255;
            int iqD1 = (__builtin_amdgcn_readlane(iqp, 48) >> 8) & 255;
            r1A = *(const float4*)(G + ((size_t)iqA1 << 8) + l4);
            r1B = *(const float4*)(G + ((size_t)iqB1 << 8) + l4);
            r1C = *(const float4*)(G + ((size_t)iqC1 << 8) + l4);
            r1D = *(const float4*)(G + ((size_t)iqD1 << 8) + l4);
            r2A = *(const float4*)(G + ((size_t)idA << 8) + l4);
            r2B = *(const float4*)(G + ((size_t)idB << 8) + l4);
            r2C = *(const float4*)(G + ((size_t)idC << 8) + l4);
            r2D = *(const float4*)(G + ((size_t)idD << 8) + l4);
        }
        // ---- Cholesky row update (verbatim; /L00==1 removed, exact) ----
        if (kk == 1) {
            float cw0 = Gs0;
            float css = cw0 * cw0;
            float om = 1.0f - css;
            L10 = cw0;
            L11 = sqrtf(fmaxf(om, 1e-12f));
        }
        if (kk == 2) {
            float cw0 = Gs0;
            float ct = Gs1 - L10 * cw0;
            float cw1 = ct / L11;
            float css = cw0 * cw0;
            float cp = cw1 * cw1; css = css + cp;
            float om = 1.0f - css;
            L20 = cw0; L21 = cw1;
            L22 = sqrtf(fmaxf(om, 1e-12f));
        }
        if (kk == 3) {
            float cw0 = Gs0;
            float ct = Gs1 - L10 * cw0;
            float cw1 = ct / L11;
            float ca = L20 * cw0;
            float cp = L21 * cw1; ca = ca + cp;
            float ct3 = Gs2 - ca;
            float cw2 = ct3 / L22;
            float css = cw0 * cw0;
            cp = cw1 * cw1; css = css + cp;
            cp = cw2 * cw2; css = css + cp;
            float om = 1.0f - css;
            L30 = cw0; L31 = cw1; L32 = cw2;
            L33 = sqrtf(fmaxf(om, 1e-12f));
        }
        // ---- forward solve, incremental (row kk only) ----
        if (kk == 0) y0 = hsel;
        if (kk == 1) { float a = L10 * y0; y1 = (hsel - a) / L11; }
        if (kk == 2) { float a = L20 * y0; float p = L21 * y1; a = a + p;
                       y2 = (hsel - a) / L22; }
        if (kk == 3) { float a = L30 * y0; float p = L31 * y1; a = a + p;
                       p = L32 * y2; a = a + p;
                       y3 = (hsel - a) / L33; }
        // ---- backward solve L^T x = y (full, cc ascending) ----
        if (kk == 0) { x0 = y0; }
        if (kk == 1) {
            x1 = y1 / L11;
            float a = L10 * x1;
            x0 = y0 - a;
        }
        if (kk == 2) {
            x2 = y2 / L22;
            float a = L21 * x2;
            x1 = (y1 - a) / L11;
            a = L10 * x1;
            float p = L20 * x2; a = a + p;
            x0 = y0 - a;
        }
        if (kk == 3) {
            x3 = y3 / L33;
            float a = L32 * x3;
            x2 = (y2 - a) / L22;
            a = L21 * x2;
            float p = L31 * x3; a = a + p;
            x1 = (y1 - a) / L11;
            a = L10 * x1;
            p = L20 * x2; a = a + p;
            p = L30 * x3; a = a + p;
            x0 = y0 - a;
        }
        // ---- residual (mul+add ascending j): row0 = cache, rows 1/2 = temps ----
        if (kk < 3) {
            float xbA0 = rdlane_f(x0, 0),  xbB0 = rdlane_f(x0, 16);
            float xbC0 = rdlane_f(x0, 32), xbD0 = rdlane_f(x0, 48);
            float xbA1 = 0.f, xbB1 = 0.f, xbC1 = 0.f, xbD1 = 0.f;
            float xbA2 = 0.f, xbB2 = 0.f, xbC2 = 0.f, xbD2 = 0.f;
            if (kk > 0) { xbA1 = rdlane_f(x1, 0);  xbB1 = rdlane_f(x1, 16);
                          xbC1 = rdlane_f(x1, 32); xbD1 = rdlane_f(x1, 48); }
            if (kk > 1) { xbA2 = rdlane_f(x2, 0);  xbB2 = rdlane_f(x2, 16);
                          xbC2 = rdlane_f(x2, 32); xbD2 = rdlane_f(x2, 48); }
            {   // signal A
                f2 bsa = (f2){xbA0, xbA0} * gA00;
                f2 bsb = (f2){xbA0, xbA0} * gA01;
                if (kk > 0) { f2 pa = (f2){xbA1, xbA1} * (f2){r1A.x, r1A.y}; bsa = bsa + pa;
                              f2 pb = (f2){xbA1, xbA1} * (f2){r1A.z, r1A.w}; bsb = bsb + pb; }
                if (kk > 1) { f2 pa = (f2){xbA2, xbA2} * (f2){r2A.x, r2A.y}; bsa = bsa + pa;
                              f2 pb = (f2){xbA2, xbA2} * (f2){r2A.z, r2A.w}; bsb = bsb + pb; }
                hA0 = sA0 - bsa;
                hA1 = sA1 - bsb;
            }
            {   // signal B
                f2 bsa = (f2){xbB0, xbB0} * gB00;
                f2 bsb = (f2){xbB0, xbB0} * gB01;
                if (kk > 0) { f2 pa = (f2){xbB1, xbB1} * (f2){r1B.x, r1B.y}; bsa = bsa + pa;
                              f2 pb = (f2){xbB1, xbB1} * (f2){r1B.z, r1B.w}; bsb = bsb + pb; }
                if (kk > 1) { f2 pa = (f2){xbB2, xbB2} * (f2){r2B.x, r2B.y}; bsa = bsa + pa;
                              f2 pb = (f2){xbB2, xbB2} * (f2){r2B.z, r2B.w}; bsb = bsb + pb; }
                hB0 = sB0 - bsa;
                hB1 = sB1 - bsb;
            }
            {   // signal C
                f2 bsa = (f2){xbC0, xbC0} * gC00;
                f2 bsb = (f2){xbC0, xbC0} * gC01;
                if (kk > 0) { f2 pa = (f2){xbC1, xbC1} * (f2){r1C.x, r1C.y}; bsa = bsa + pa;
                              f2 pb = (f2){xbC1, xbC1} * (f2){r1C.z, r1C.w}; bsb = bsb + pb; }
                if (kk > 1) { f2 pa = (f2){xbC2, xbC2} * (f2){r2C.x, r2C.y}; bsa = bsa + pa;
                              f2 pb = (f2){xbC2, xbC2} * (f2){r2C.z, r2C.w}; bsb = bsb + pb; }
                hC0 = sC0 - bsa;
                hC1 = sC1 - bsb;
            }
            {   // signal D
                f2 bsa = (f2){xbD0, xbD0} * gD00;
                f2 bsb = (f2){xbD0, xbD0} * gD01;
                if (kk > 0) { f2 pa = (f2){xbD1, xbD1} * (f2){r1D.x, r1D.y}; bsa = bsa + pa;
                              f2 pb = (f2){xbD1, xbD1} * (f2){r1D.z, r1D.w}; bsb = bsb + pb; }
                if (kk > 1) { f2 pa = (f2){xbD2, xbD2} * (f2){r2D.x, r2D.y}; bsa = bsa + pa;
                              f2 pb = (f2){xbD2, xbD2} * (f2){r2D.z, r2D.w}; bsb = bsb + pb; }
                hD0 = sD0 - bsa;
                hD1 = sD1 - bsb;
            }
        }
    }
    // quarter-lead lanes (0,16,32,48) write their signal's coeffs + support
    if ((lane & 15) == 0) {
        int s = s0 + qt;
        xsv[0 * SIGS_B + s] = x0; xsv[1 * SIGS_B + s] = x1;
        xsv[2 * SIGS_B + s] = x2; xsv[3 * SIGS_B + s] = x3;
        qi[0 * SIGS_B + s] = iqp & 255;
        qi[1 * SIGS_B + s] = (iqp >> 8) & 255;
        qi[2 * SIGS_B + s] = (iqp >> 16) & 255;
        qi[3 * SIGS_B + s] = (iqp >> 24) & 255;
    }
}

// __launch_bounds__(256, 2): proven clean allocator point (R10: VGPR 112,
// zero scratch, WRITE collapsed 98->33MB = ideal). R11 trims the working
// set (one cached G row instead of three) targeting VGPR <=85 -> 6
// waves/SIMD occupancy tier (512-VGPR pool: <=102 -> 5, <=85 -> 6).
__launch_bounds__(THREADS, 2)
__global__ void k_omp(const float* __restrict__ z,
                      const float* __restrict__ Dn_g,
                      const float* __restrict__ DnT_g,
                      const float* __restrict__ G,
                      double* __restrict__ loss_acc,
                      unsigned int* __restrict__ ctr,
                      float* __restrict__ zq,
                      float* __restrict__ loss_out)
{
    extern __shared__ char smem[];
    float* sig = (float*)(smem + LB_SIG);
    float* xsv = (float*)(smem + LB_XS);
    int* qi = (int*)(smem + LB_QI);
    double* red = (double*)(smem + LB_RED);

    int tid = threadIdx.x;
    int lane = tid & 63;
    int qt = lane >> 4;          // lane quarter = signal slot within quad
    int wid = tid >> 6;          // 0..3

    long sbase = (long)blockIdx.x * SIGS_B;  // 64 consecutive pixels, one batch b
    int b = (int)(sbase >> 12);
    int pl0 = (int)(sbase & 4095);
    const float* zb = z + ((size_t)b << 18) + pl0;
    // stage z_e -> sig[c][w], coalesced along w
    {
        int w = tid & (SIGS_B - 1);
        int g = tid >> 6;
#pragma unroll
        for (int i = 0; i < 16; i++) {
            int c = g * 16 + i;
            sig[c * SIGS_B + w] = zb[(size_t)c * 4096 + w];
        }
    }
    __syncthreads();

    // each wave: 16 signals in 2 groups of 8; h_bar = X^T Dn, fp32 fused-FMA
    // sequential over c ascending, packed as float2 -> v_pk_fma_f32.
    // h_bar fragments are NAMED f2 scalars (no array -> no scratch risk).
    for (int g2 = 0; g2 < 2; g2++) {
        int s0 = wid * 16 + g2 * 8;
        f2 h00 = {0.f, 0.f}, h01 = {0.f, 0.f};
        f2 h10 = {0.f, 0.f}, h11 = {0.f, 0.f};
        f2 h20 = {0.f, 0.f}, h21 = {0.f, 0.f};
        f2 h30 = {0.f, 0.f}, h31 = {0.f, 0.f};
        f2 h40 = {0.f, 0.f}, h41 = {0.f, 0.f};
        f2 h50 = {0.f, 0.f}, h51 = {0.f, 0.f};
        f2 h60 = {0.f, 0.f}, h61 = {0.f, 0.f};
        f2 h70 = {0.f, 0.f}, h71 = {0.f, 0.f};
#pragma unroll 8
        for (int c = 0; c < DIM; c++) {
            float4 sva = *(const float4*)(sig + c * SIGS_B + s0);
            float4 svb = *(const float4*)(sig + c * SIGS_B + s0 + 4);
            float4 dv = *(const float4*)(Dn_g + c * NEMB + 4 * lane);
            f2 d0 = {dv.x, dv.y};
            f2 d1 = {dv.z, dv.w};
            h00 = __builtin_elementwise_fma((f2){sva.x, sva.x}, d0, h00);
            h01 = __builtin_elementwise_fma((f2){sva.x, sva.x}, d1, h01);
            h10 = __builtin_elementwise_fma((f2){sva.y, sva.y}, d0, h10);
            h11 = __builtin_elementwise_fma((f2){sva.y, sva.y}, d1, h11);
            h20 = __builtin_elementwise_fma((f2){sva.z, sva.z}, d0, h20);
            h21 = __builtin_elementwise_fma((f2){sva.z, sva.z}, d1, h21);
            h30 = __builtin_elementwise_fma((f2){sva.w, sva.w}, d0, h30);
            h31 = __builtin_elementwise_fma((f2){sva.w, sva.w}, d1, h31);
            h40 = __builtin_elementwise_fma((f2){svb.x, svb.x}, d0, h40);
            h41 = __builtin_elementwise_fma((f2){svb.x, svb.x}, d1, h41);
            h50 = __builtin_elementwise_fma((f2){svb.y, svb.y}, d0, h50);
            h51 = __builtin_elementwise_fma((f2){svb.y, svb.y}, d1, h51);
            h60 = __builtin_elementwise_fma((f2){svb.z, svb.z}, d0, h60);
            h61 = __builtin_elementwise_fma((f2){svb.z, svb.z}, d1, h61);
            h70 = __builtin_elementwise_fma((f2){svb.w, svb.w}, d0, h70);
            h71 = __builtin_elementwise_fma((f2){svb.w, svb.w}, d1, h71);
        }
        omp_quad4(h00, h01, h10, h11, h20, h21, h30, h31,
                  lane, qt, G, xsv, qi, s0);
        omp_quad4(h40, h41, h50, h51, h60, h61, h70, h71,
                  lane, qt, G, xsv, qi, s0 + 4);
    }
    __syncthreads();

    // thread-parallel mu-law quantize of all 256 coeffs (one per thread)
    {
        int jq = tid >> 6;
        int wq = tid & (SIGS_B - 1);
        xsv[jq * SIGS_B + wq] = quant_decode(xsv[jq * SIGS_B + wq]);
    }
    __syncthreads();

    // store phase: recon (einsum order: mul+add, k ascending, no fma),
    // gathers vectorized via DnT (DnT[i][c] == Dn[c][i], bit-identical).
    double lsum = 0.0;
    float* zqb = zq + ((size_t)b << 18) + pl0;
    {
#pragma clang fp contract(off)
        int w = tid & (SIGS_B - 1);
        int g = tid >> 6;
        float q0 = xsv[0 * SIGS_B + w], q1 = xsv[1 * SIGS_B + w];
        float q2 = xsv[2 * SIGS_B + w], q3 = xsv[3 * SIGS_B + w];
        int i0 = qi[0 * SIGS_B + w], i1 = qi[1 * SIGS_B + w];
        int i2 = qi[2 * SIGS_B + w], i3 = qi[3 * SIGS_B + w];
        const float* t0p = DnT_g + (i0 << 6) + (g << 4);
        const float* t1p = DnT_g + (i1 << 6) + (g << 4);
        const float* t2p = DnT_g + (i2 << 6) + (g << 4);
        const float* t3p = DnT_g + (i3 << 6) + (g << 4);
#pragma unroll
        for (int cb = 0; cb < 4; cb++) {
            float4 d0 = *(const float4*)(t0p + 4 * cb);
            float4 d1 = *(const float4*)(t1p + 4 * cb);
            float4 d2 = *(const float4*)(t2p + 4 * cb);
            float4 d3 = *(const float4*)(t3p + 4 * cb);
#pragma unroll
            for (int u = 0; u < 4; u++) {
                int c = (g << 4) + (cb << 2) + u;
                float e0 = (u == 0) ? d0.x : (u == 1) ? d0.y : (u == 2) ? d0.z : d0.w;
                float e1 = (u == 0) ? d1.x : (u == 1) ? d1.y : (u == 2) ? d1.z : d1.w;
                float e2 = (u == 0) ? d2.x : (u == 1) ? d2.y : (u == 2) ? d2.z : d2.w;
                float e3 = (u == 0) ? d3.x : (u == 1) ? d3.y : (u == 2) ? d3.z : d3.w;
                float p0 = q0 * e0;
                float p1 = q1 * e1;
                float p2 = q2 * e2;
                float p3 = q3 * e3;
                float r = p0 + p1;
                r = r + p2;
                r = r + p3;
                float zev = sig[c * SIGS_B + w];
                float d = r - zev;
                float zqv = zev + d;           // z_q = z_e + (recon - z_e)
                lsum += (double)d * (double)d;
                zqb[(size_t)c * 4096 + w] = zqv;
            }
        }
    }
#pragma unroll
    for (int off = 32; off > 0; off >>= 1) lsum += __shfl_xor(lsum, off);
    if (lane == 0) red[wid] = lsum;
    __syncthreads();
    if (tid == 0) {
        double t = 0.0;
#pragma unroll
        for (int i = 0; i < 4; i++) t += red[i];
        atomicAdd(loss_acc, t);
        __threadfence();
        unsigned int done = atomicAdd(ctr, 1u);
        if (done == GRID - 1) {
            double m = atomicAdd(loss_acc, 0.0) / 8388608.0;
            loss_out[0] = (float)(m + 0.25 * m);
        }
    }
}

extern "C" void kernel_launch(void* const* d_in, const int* in_sizes, int n_in,
                              void* d_out, int out_size, void* d_ws, size_t ws_size,
                              hipStream_t stream)
{
    const float* z = (const float*)d_in[0];
    const float* D = (const float*)d_in[1];
    float* out = (float*)d_out;
    char* ws = (char*)d_ws;
    double* loss_acc = (double*)ws;                       // 8 B
    unsigned int* ctr = (unsigned int*)(ws + 8);          // 4 B
    float* Dn = (float*)(ws + 256);                       // 64x256 f32
    float* G = (float*)(ws + 256 + 65536);                // 256x256 f32
    float* DnT = (float*)(ws + 256 + 65536 + 262144);     // 256x64 f32

    k_ng<<<NEMB, NEMB, 0, stream>>>(D, Dn, DnT, G, loss_acc, ctr);
    hipFuncSetAttribute(reinterpret_cast<const void*>(k_omp),
                        hipFuncAttributeMaxDynamicSharedMemorySize, LDS_BYTES);
    k_omp<<<GRID, THREADS, LDS_BYTES, stream>>>(z, Dn, DnT, G, loss_acc, ctr, out, out + 8388608);
    (void)in_sizes; (void)n_in; (void)out_size; (void)ws_size;
}

// Round 12
// 261.003 us; speedup vs baseline: 1.1029x; 1.1029x over previous
//
#include <hip/hip_runtime.h>
#include <math.h>

#define NEMB 256
#define DIM 64
#define SIGS_B 64                 // signals per block
#define THREADS 256               // 4 waves per block
#define NSIG 131072
#define GRID (NSIG / SIGS_B)      // 2048

#define LOG1P50 3.9318256327243257        // np.log1p(50.0), f64
#define INV_MU_F ((float)(1.0 / LOG1P50)) // fp32-rounded scalar, as numpy uses
#define TWO15_F ((float)(2.0 / 15.0))

// dynamic LDS layout (byte offsets) — Dn NOT staged (L2-hot from global)
#define LB_SIG   0          // 16384 B : sig f32 [c][w]  (64 x 64)
#define LB_XS    16384      // 1024 B  : raw coeffs f32 [4][SIGS_B]
#define LB_QI    17408      // 1024 B  : qi i32 [4][SIGS_B]
#define LB_RED   18432      // 32 B    : per-wave loss partials (f64)
#define LDS_BYTES 18464

typedef float f2 __attribute__((ext_vector_type(2)));

__device__ __forceinline__ float rdlane_f(float v, int lane)
{
    return __builtin_bit_cast(float, __builtin_amdgcn_readlane(__builtin_bit_cast(int, v), lane));
}

template<int CTRL>
__device__ __forceinline__ float dpp_fmax(float m)
{
    int sh = __builtin_amdgcn_update_dpp(0, __builtin_bit_cast(int, m), CTRL, 0xf, 0xf, true);
    return fmaxf(m, __builtin_bit_cast(float, sh));
}

// wave-wide max of non-negative values; valid in lane 63. Pure VALU (DPP).
__device__ __forceinline__ float wave_max_nn(float v)
{
    v = dpp_fmax<0x111>(v);   // row_shr:1
    v = dpp_fmax<0x112>(v);   // row_shr:2
    v = dpp_fmax<0x114>(v);   // row_shr:4
    v = dpp_fmax<0x118>(v);   // row_shr:8  -> lane 15/31/47/63 = row max
    v = dpp_fmax<0x142>(v);   // row_bcast:15 -> lane 31/63 = half max
    v = dpp_fmax<0x143>(v);   // row_bcast:31 -> lane 63 = wave max
    return v;
}

// Fused normalize + gram (+ DnT transpose for the store-phase vector gathers).
__global__ void k_ng(const float* __restrict__ D, float* __restrict__ Dn,
                     float* __restrict__ DnT, float* __restrict__ G,
                     double* __restrict__ loss_acc, unsigned int* __restrict__ ctr)
{
#pragma clang fp contract(off)
    __shared__ float nrmS[NEMB];
    __shared__ float coli[DIM];
    int i = blockIdx.x, j = threadIdx.x;
    if (i == 0 && j == 0) { loss_acc[0] = 0.0; ctr[0] = 0u; }
    float ss = 0.0f;
    for (int c = 0; c < DIM; c++) {
        float v = D[c * NEMB + j];
        float sq = v * v;
        ss = ss + sq;
    }
    float nrm = fmaxf(sqrtf(ss), 1e-10f);
    nrmS[j] = nrm;
    __syncthreads();
    if (j < DIM) {
        float dni = D[j * NEMB + i] / nrmS[i];
        coli[j] = dni;
        Dn[j * NEMB + i] = dni;         // block i owns Dn column i
        DnT[i * DIM + j] = dni;         // and DnT row i (same bits)
    }
    __syncthreads();
    float s = 0.0f;
#pragma unroll 8
    for (int c = 0; c < DIM; c++) {
        float dnj = D[c * NEMB + j] / nrm;     // rounds identically to Dn[c][j]
        s = fmaf(coli[c], dnj, s);
    }
    G[i * NEMB + j] = s;
}

// mu-law quantize+decode, all fp32, numpy op-for-op (no fusion)
__device__ __forceinline__ float quant_decode(float coeff)
{
#pragma clang fp contract(off)
    float c = fminf(fmaxf(coeff, -3.0f), 3.0f) / 3.0f;
    float ac = fabsf(c);
    float sgn = (c > 0.0f) ? 1.0f : ((c < 0.0f) ? -1.0f : 0.0f);
    float l = log1pf(ac * 50.0f);
    float enc = (sgn * l) * INV_MU_F;
    float scaled = (enc + 1.0f) * 7.5f;
    int bin = (int)rintf(scaled);              // round-half-even == np.round
    bin = bin < 0 ? 0 : (bin > 15 ? 15 : bin);
    float t = (float)bin * TWO15_F;
    float zv = t - 1.0f;
    float az = fabsf(zv);
    float sz = (zv > 0.0f) ? 1.0f : ((zv < 0.0f) ? -1.0f : 0.0f);
    float e = expm1f(az / INV_MU_F);
    return (sz * (e / 50.0f)) * 3.0f;
}

// FOUR signals' OMP (K=4) per call, fully scalarized (no arrays anywhere:
// every piece of state is a named scalar or by-value f2 -> SROA cannot fail,
// nothing can reach scratch). Selection/residual distributed over all 64
// lanes (4 atoms/lane); Cholesky+solves run ONCE on quarter-selected
// operands (lanes 16m..16m+15 = signal m).
// G-row handling = round-1's register-cache pattern on the quad: all three
// selected atoms' G rows cached at selection time (float4/lane, uniform
// base + 4*lane, issued before chol -> latency hidden); Gs = G[Iv_j][idx]
// extracted from cached rows via cndmask tree + readlane (~30cy VALU, no
// memory op on the chol critical path); residual reuses the cached rows.
// R10 verified: VGPR 112, zero scratch (WRITE 98->33MB ideal), k_omp 200us.
// R11's cache trim (1 row + direct Gs loads) bought VGPR 84 / +44% occupancy
// but LOST 14% — measured residency is ~0.4x allowed in every config, so
// occupancy gains don't pay; chol-chain memory latency costs 1:1. Keep R10.
__device__ __forceinline__ void omp_quad4(
    f2 sA0, f2 sA1, f2 sB0, f2 sB1, f2 sC0, f2 sC1, f2 sD0, f2 sD1,
    int lane, int qt,
    const float* __restrict__ G,
    float* __restrict__ xsv, int* __restrict__ qi, int s0)
{
#pragma clang fp contract(off)
    f2 hA0 = sA0, hA1 = sA1, hB0 = sB0, hB1 = sB1;
    f2 hC0 = sC0, hC1 = sC1, hD0 = sD0, hD1 = sD1;
    int m4A = 0, m4B = 0, m4C = 0, m4D = 0;
    f2 gA00, gA01, gA10, gA11, gA20, gA21;        // cached G rows, signal A
    f2 gB00, gB01, gB10, gB11, gB20, gB21;
    f2 gC00, gC01, gC10, gC11, gC20, gC21;
    f2 gD00, gD01, gD10, gD11, gD20, gD21;
    int iq0 = 0, iq1 = 0, iq2 = 0, iq3 = 0;       // quarter-selected support
    float L10, L11, L20, L21, L22, L30, L31, L32, L33;
    float y0, y1, y2, y3;
    float x0 = 0.f, x1 = 0.f, x2 = 0.f, x3 = 0.f;
#pragma unroll
    for (int kk = 0; kk < 4; kk++) {
        // ---- per-lane best of own 4 atoms (ascending j, strict >) x4 ----
        float aA0 = (m4A & 1) ? 0.f : fabsf(hA0[0]);
        float aA1 = (m4A & 2) ? 0.f : fabsf(hA0[1]);
        float aA2 = (m4A & 4) ? 0.f : fabsf(hA1[0]);
        float aA3 = (m4A & 8) ? 0.f : fabsf(hA1[1]);
        float bvA = aA0; int bjA = 0;
        if (aA1 > bvA) { bvA = aA1; bjA = 1; }
        if (aA2 > bvA) { bvA = aA2; bjA = 2; }
        if (aA3 > bvA) { bvA = aA3; bjA = 3; }
        float aB0 = (m4B & 1) ? 0.f : fabsf(hB0[0]);
        float aB1 = (m4B & 2) ? 0.f : fabsf(hB0[1]);
        float aB2 = (m4B & 4) ? 0.f : fabsf(hB1[0]);
        float aB3 = (m4B & 8) ? 0.f : fabsf(hB1[1]);
        float bvB = aB0; int bjB = 0;
        if (aB1 > bvB) { bvB = aB1; bjB = 1; }
        if (aB2 > bvB) { bvB = aB2; bjB = 2; }
        if (aB3 > bvB) { bvB = aB3; bjB = 3; }
        float aC0 = (m4C & 1) ? 0.f : fabsf(hC0[0]);
        float aC1 = (m4C & 2) ? 0.f : fabsf(hC0[1]);
        float aC2 = (m4C & 4) ? 0.f : fabsf(hC1[0]);
        float aC3 = (m4C & 8) ? 0.f : fabsf(hC1[1]);
        float bvC = aC0; int bjC = 0;
        if (aC1 > bvC) { bvC = aC1; bjC = 1; }
        if (aC2 > bvC) { bvC = aC2; bjC = 2; }
        if (aC3 > bvC) { bvC = aC3; bjC = 3; }
        float aD0 = (m4D & 1) ? 0.f : fabsf(hD0[0]);
        float aD1 = (m4D & 2) ? 0.f : fabsf(hD0[1]);
        float aD2 = (m4D & 4) ? 0.f : fabsf(hD1[0]);
        float aD3 = (m4D & 8) ? 0.f : fabsf(hD1[1]);
        float bvD = aD0; int bjD = 0;
        if (aD1 > bvD) { bvD = aD1; bjD = 1; }
        if (aD2 > bvD) { bvD = aD2; bjD = 2; }
        if (aD3 > bvD) { bvD = aD3; bjD = 3; }
        // ---- wave max (value only) x4, then first-lane tie-break ----
        float rA = wave_max_nn(bvA);
        float rB = wave_max_nn(bvB);
        float rC = wave_max_nn(bvC);
        float rD = wave_max_nn(bvD);
        float vmA = rdlane_f(rA, 63), vmB = rdlane_f(rB, 63);
        float vmC = rdlane_f(rC, 63), vmD = rdlane_f(rD, 63);
        unsigned long long blA = __ballot(bvA == vmA);
        unsigned long long blB = __ballot(bvB == vmB);
        unsigned long long blC = __ballot(bvC == vmC);
        unsigned long long blD = __ballot(bvD == vmD);
        int owA = __ffsll((long long)blA) - 1;
        int owB = __ffsll((long long)blB) - 1;
        int owC = __ffsll((long long)blC) - 1;
        int owD = __ffsll((long long)blD) - 1;
        int boA = __builtin_amdgcn_readlane(bjA, owA);
        int boB = __builtin_amdgcn_readlane(bjB, owB);
        int boC = __builtin_amdgcn_readlane(bjC, owC);
        int boD = __builtin_amdgcn_readlane(bjD, owD);
        int idA = 4 * owA + boA;       // uniform
        int idB = 4 * owB + boB;
        int idC = 4 * owC + boC;
        int idD = 4 * owD + boD;
        m4A |= (lane == owA) ? (1 << boA) : 0;
        m4B |= (lane == owB) ? (1 << boB) : 0;
        m4C |= (lane == owC) ? (1 << boC) : 0;
        m4D |= (lane == owD) ? (1 << boD) : 0;
        // ---- original h_bar at selected atom ----
        float tvA = sA0[0];
        tvA = (bjA == 1) ? sA0[1] : tvA;
        tvA = (bjA == 2) ? sA1[0] : tvA;
        tvA = (bjA == 3) ? sA1[1] : tvA;
        float tvB = sB0[0];
        tvB = (bjB == 1) ? sB0[1] : tvB;
        tvB = (bjB == 2) ? sB1[0] : tvB;
        tvB = (bjB == 3) ? sB1[1] : tvB;
        float tvC = sC0[0];
        tvC = (bjC == 1) ? sC0[1] : tvC;
        tvC = (bjC == 2) ? sC1[0] : tvC;
        tvC = (bjC == 3) ? sC1[1] : tvC;
        float tvD = sD0[0];
        tvD = (bjD == 1) ? sD0[1] : tvD;
        tvD = (bjD == 2) ? sD1[0] : tvD;
        tvD = (bjD == 3) ? sD1[1] : tvD;
        float hsA = rdlane_f(tvA, owA);
        float hsB = rdlane_f(tvB, owB);
        float hsC = rdlane_f(tvC, owC);
        float hsD = rdlane_f(tvD, owD);
        float hsel = (qt & 2) ? ((qt & 1) ? hsD : hsC) : ((qt & 1) ? hsB : hsA);
        int idxq = (qt & 2) ? ((qt & 1) ? idD : idC) : ((qt & 1) ? idB : idA);
        if (kk == 0) iq0 = idxq;
        if (kk == 1) iq1 = idxq;
        if (kk == 2) iq2 = idxq;
        if (kk == 3) iq3 = idxq;
        // ---- cache this round's G rows (issued early, consumed in residual) ----
        const int l4 = 4 * lane;
        if (kk < 3) {
            float4 ra = *(const float4*)(G + ((size_t)idA << 8) + l4);
            float4 rb = *(const float4*)(G + ((size_t)idB << 8) + l4);
            float4 rc = *(const float4*)(G + ((size_t)idC << 8) + l4);
            float4 rd = *(const float4*)(G + ((size_t)idD << 8) + l4);
            if (kk == 0) {
                gA00 = (f2){ra.x, ra.y}; gA01 = (f2){ra.z, ra.w};
                gB00 = (f2){rb.x, rb.y}; gB01 = (f2){rb.z, rb.w};
                gC00 = (f2){rc.x, rc.y}; gC01 = (f2){rc.z, rc.w};
                gD00 = (f2){rd.x, rd.y}; gD01 = (f2){rd.z, rd.w};
            }
            if (kk == 1) {
                gA10 = (f2){ra.x, ra.y}; gA11 = (f2){ra.z, ra.w};
                gB10 = (f2){rb.x, rb.y}; gB11 = (f2){rb.z, rb.w};
                gC10 = (f2){rc.x, rc.y}; gC11 = (f2){rc.z, rc.w};
                gD10 = (f2){rd.x, rd.y}; gD11 = (f2){rd.z, rd.w};
            }
            if (kk == 2) {
                gA20 = (f2){ra.x, ra.y}; gA21 = (f2){ra.z, ra.w};
                gB20 = (f2){rb.x, rb.y}; gB21 = (f2){rb.z, rb.w};
                gC20 = (f2){rc.x, rc.y}; gC21 = (f2){rc.z, rc.w};
                gD20 = (f2){rd.x, rd.y}; gD21 = (f2){rd.z, rd.w};
            }
        }
        // ---- Gs = G[Iv_j][idx] by in-register extraction (no memory) ----
        float Gs0 = 0.f, Gs1 = 0.f, Gs2 = 0.f;
        if (kk > 0) {
            float eA = gA00[0];
            eA = (boA == 1) ? gA00[1] : eA;
            eA = (boA == 2) ? gA01[0] : eA;
            eA = (boA == 3) ? gA01[1] : eA;
            float eB = gB00[0];
            eB = (boB == 1) ? gB00[1] : eB;
            eB = (boB == 2) ? gB01[0] : eB;
            eB = (boB == 3) ? gB01[1] : eB;
            float eC = gC00[0];
            eC = (boC == 1) ? gC00[1] : eC;
            eC = (boC == 2) ? gC01[0] : eC;
            eC = (boC == 3) ? gC01[1] : eC;
            float eD = gD00[0];
            eD = (boD == 1) ? gD00[1] : eD;
            eD = (boD == 2) ? gD01[0] : eD;
            eD = (boD == 3) ? gD01[1] : eD;
            float GsA = rdlane_f(eA, owA);
            float GsB = rdlane_f(eB, owB);
            float GsC = rdlane_f(eC, owC);
            float GsD = rdlane_f(eD, owD);
            Gs0 = (qt & 2) ? ((qt & 1) ? GsD : GsC) : ((qt & 1) ? GsB : GsA);
        }
        if (kk > 1) {
            float eA = gA10[0];
            eA = (boA == 1) ? gA10[1] : eA;
            eA = (boA == 2) ? gA11[0] : eA;
            eA = (boA == 3) ? gA11[1] : eA;
            float eB = gB10[0];
            eB = (boB == 1) ? gB10[1] : eB;
            eB = (boB == 2) ? gB11[0] : eB;
            eB = (boB == 3) ? gB11[1] : eB;
            float eC = gC10[0];
            eC = (boC == 1) ? gC10[1] : eC;
            eC = (boC == 2) ? gC11[0] : eC;
            eC = (boC == 3) ? gC11[1] : eC;
            float eD = gD10[0];
            eD = (boD == 1) ? gD10[1] : eD;
            eD = (boD == 2) ? gD11[0] : eD;
            eD = (boD == 3) ? gD11[1] : eD;
            float GsA = rdlane_f(eA, owA);
            float GsB = rdlane_f(eB, owB);
            float GsC = rdlane_f(eC, owC);
            float GsD = rdlane_f(eD, owD);
            Gs1 = (qt & 2) ? ((qt & 1) ? GsD : GsC) : ((qt & 1) ? GsB : GsA);
        }
        if (kk > 2) {
            float eA = gA20[0];
            eA = (boA == 1) ? gA20[1] : eA;
            eA = (boA == 2) ? gA21[0] : eA;
            eA = (boA == 3) ? gA21[1] : eA;
            float eB = gB20[0];
            eB = (boB == 1) ? gB20[1] : eB;
            eB = (boB == 2) ? gB21[0] : eB;
            eB = (boB == 3) ? gB21[1] : eB;
            float eC = gC20[0];
            eC = (boC == 1) ? gC20[1] : eC;
            eC = (boC == 2) ? gC21[0] : eC;
            eC = (boC == 3) ? gC21[1] : eC;
            float eD = gD20[0];
            eD = (boD == 1) ? gD20[1] : eD;
            eD = (boD == 2) ? gD21[0] : eD;
            eD = (boD == 3) ? gD21[1] : eD;
            float GsA = rdlane_f(eA, owA);
            float GsB = rdlane_f(eB, owB);
            float GsC = rdlane_f(eC, owC);
            float GsD = rdlane_f(eD, owD);
            Gs2 = (qt & 2) ? ((qt & 1) ? GsD : GsC) : ((qt & 1) ? GsB : GsA);
        }
        // ---- Cholesky row update (verbatim; /L00==1 removed, exact) ----
        if (kk == 1) {
            float cw0 = Gs0;
            float css = cw0 * cw0;
            float om = 1.0f - css;
            L10 = cw0;
            L11 = sqrtf(fmaxf(om, 1e-12f));
        }
        if (kk == 2) {
            float cw0 = Gs0;
            float ct = Gs1 - L10 * cw0;
            float cw1 = ct / L11;
            float css = cw0 * cw0;
            float cp = cw1 * cw1; css = css + cp;
            float om = 1.0f - css;
            L20 = cw0; L21 = cw1;
            L22 = sqrtf(fmaxf(om, 1e-12f));
        }
        if (kk == 3) {
            float cw0 = Gs0;
            float ct = Gs1 - L10 * cw0;
            float cw1 = ct / L11;
            float ca = L20 * cw0;
            float cp = L21 * cw1; ca = ca + cp;
            float ct3 = Gs2 - ca;
            float cw2 = ct3 / L22;
            float css = cw0 * cw0;
            cp = cw1 * cw1; css = css + cp;
            cp = cw2 * cw2; css = css + cp;
            float om = 1.0f - css;
            L30 = cw0; L31 = cw1; L32 = cw2;
            L33 = sqrtf(fmaxf(om, 1e-12f));
        }
        // ---- forward solve, incremental (row kk only) ----
        if (kk == 0) y0 = hsel;
        if (kk == 1) { float a = L10 * y0; y1 = (hsel - a) / L11; }
        if (kk == 2) { float a = L20 * y0; float p = L21 * y1; a = a + p;
                       y2 = (hsel - a) / L22; }
        if (kk == 3) { float a = L30 * y0; float p = L31 * y1; a = a + p;
                       p = L32 * y2; a = a + p;
                       y3 = (hsel - a) / L33; }
        // ---- backward solve L^T x = y (full, cc ascending) ----
        if (kk == 0) { x0 = y0; }
        if (kk == 1) {
            x1 = y1 / L11;
            float a = L10 * x1;
            x0 = y0 - a;
        }
        if (kk == 2) {
            x2 = y2 / L22;
            float a = L21 * x2;
            x1 = (y1 - a) / L11;
            a = L10 * x1;
            float p = L20 * x2; a = a + p;
            x0 = y0 - a;
        }
        if (kk == 3) {
            x3 = y3 / L33;
            float a = L32 * x3;
            x2 = (y2 - a) / L22;
            a = L21 * x2;
            float p = L31 * x3; a = a + p;
            x1 = (y1 - a) / L11;
            a = L10 * x1;
            p = L20 * x2; a = a + p;
            p = L30 * x3; a = a + p;
            x0 = y0 - a;
        }
        // ---- residual from cached rows (mul+add ascending j) ----
        if (kk < 3) {
            float xbA0 = rdlane_f(x0, 0),  xbB0 = rdlane_f(x0, 16);
            float xbC0 = rdlane_f(x0, 32), xbD0 = rdlane_f(x0, 48);
            float xbA1 = 0.f, xbB1 = 0.f, xbC1 = 0.f, xbD1 = 0.f;
            float xbA2 = 0.f, xbB2 = 0.f, xbC2 = 0.f, xbD2 = 0.f;
            if (kk > 0) { xbA1 = rdlane_f(x1, 0);  xbB1 = rdlane_f(x1, 16);
                          xbC1 = rdlane_f(x1, 32); xbD1 = rdlane_f(x1, 48); }
            if (kk > 1) { xbA2 = rdlane_f(x2, 0);  xbB2 = rdlane_f(x2, 16);
                          xbC2 = rdlane_f(x2, 32); xbD2 = rdlane_f(x2, 48); }
            {   // signal A
                f2 bsa = (f2){xbA0, xbA0} * gA00;
                f2 bsb = (f2){xbA0, xbA0} * gA01;
                if (kk > 0) { f2 pa = (f2){xbA1, xbA1} * gA10; bsa = bsa + pa;
                              f2 pb = (f2){xbA1, xbA1} * gA11; bsb = bsb + pb; }
                if (kk > 1) { f2 pa = (f2){xbA2, xbA2} * gA20; bsa = bsa + pa;
                              f2 pb = (f2){xbA2, xbA2} * gA21; bsb = bsb + pb; }
                hA0 = sA0 - bsa;
                hA1 = sA1 - bsb;
            }
            {   // signal B
                f2 bsa = (f2){xbB0, xbB0} * gB00;
                f2 bsb = (f2){xbB0, xbB0} * gB01;
                if (kk > 0) { f2 pa = (f2){xbB1, xbB1} * gB10; bsa = bsa + pa;
                              f2 pb = (f2){xbB1, xbB1} * gB11; bsb = bsb + pb; }
                if (kk > 1) { f2 pa = (f2){xbB2, xbB2} * gB20; bsa = bsa + pa;
                              f2 pb = (f2){xbB2, xbB2} * gB21; bsb = bsb + pb; }
                hB0 = sB0 - bsa;
                hB1 = sB1 - bsb;
            }
            {   // signal C
                f2 bsa = (f2){xbC0, xbC0} * gC00;
                f2 bsb = (f2){xbC0, xbC0} * gC01;
                if (kk > 0) { f2 pa = (f2){xbC1, xbC1} * gC10; bsa = bsa + pa;
                              f2 pb = (f2){xbC1, xbC1} * gC11; bsb = bsb + pb; }
                if (kk > 1) { f2 pa = (f2){xbC2, xbC2} * gC20; bsa = bsa + pa;
                              f2 pb = (f2){xbC2, xbC2} * gC21; bsb = bsb + pb; }
                hC0 = sC0 - bsa;
                hC1 = sC1 - bsb;
            }
            {   // signal D
                f2 bsa = (f2){xbD0, xbD0} * gD00;
                f2 bsb = (f2){xbD0, xbD0} * gD01;
                if (kk > 0) { f2 pa = (f2){xbD1, xbD1} * gD10; bsa = bsa + pa;
                              f2 pb = (f2){xbD1, xbD1} * gD11; bsb = bsb + pb; }
                if (kk > 1) { f2 pa = (f2){xbD2, xbD2} * gD20; bsa = bsa + pa;
                              f2 pb = (f2){xbD2, xbD2} * gD21; bsb = bsb + pb; }
                hD0 = sD0 - bsa;
                hD1 = sD1 - bsb;
            }
        }
    }
    // quarter-lead lanes (0,16,32,48) write their signal's coeffs + support
    if ((lane & 15) == 0) {
        int s = s0 + qt;
        xsv[0 * SIGS_B + s] = x0; xsv[1 * SIGS_B + s] = x1;
        xsv[2 * SIGS_B + s] = x2; xsv[3 * SIGS_B + s] = x3;
        qi[0 * SIGS_B + s] = iq0; qi[1 * SIGS_B + s] = iq1;
        qi[2 * SIGS_B + s] = iq2; qi[3 * SIGS_B + s] = iq3;
    }
}

// __launch_bounds__(256, 2): min 2 waves/EU -> VGPR cap 256. R10 verified:
// the allocator picks 112 VGPR with ZERO scratch (WRITE collapsed 98->33MB
// = z_q ideal; k_omp 236->200us). Tighter caps (128/85/64) made the
// allocator choose 64/40/32 and spill the OMP working set (R4/R5/R8).
// R11's register trim to 84 (+44% occupancy) LOST 14%: measured residency
// is ~0.4x resource-allowed in every config, so occupancy gains don't pay.
__launch_bounds__(THREADS, 2)
__global__ void k_omp(const float* __restrict__ z,
                      const float* __restrict__ Dn_g,
                      const float* __restrict__ DnT_g,
                      const float* __restrict__ G,
                      double* __restrict__ loss_acc,
                      unsigned int* __restrict__ ctr,
                      float* __restrict__ zq,
                      float* __restrict__ loss_out)
{
    extern __shared__ char smem[];
    float* sig = (float*)(smem + LB_SIG);
    float* xsv = (float*)(smem + LB_XS);
    int* qi = (int*)(smem + LB_QI);
    double* red = (double*)(smem + LB_RED);

    int tid = threadIdx.x;
    int lane = tid & 63;
    int qt = lane >> 4;          // lane quarter = signal slot within quad
    int wid = tid >> 6;          // 0..3

    long sbase = (long)blockIdx.x * SIGS_B;  // 64 consecutive pixels, one batch b
    int b = (int)(sbase >> 12);
    int pl0 = (int)(sbase & 4095);
    const float* zb = z + ((size_t)b << 18) + pl0;
    // stage z_e -> sig[c][w], coalesced along w
    {
        int w = tid & (SIGS_B - 1);
        int g = tid >> 6;
#pragma unroll
        for (int i = 0; i < 16; i++) {
            int c = g * 16 + i;
            sig[c * SIGS_B + w] = zb[(size_t)c * 4096 + w];
        }
    }
    __syncthreads();

    // each wave: 16 signals in 2 groups of 8; h_bar = X^T Dn, fp32 fused-FMA
    // sequential over c ascending, packed as float2 -> v_pk_fma_f32.
    // h_bar fragments are NAMED f2 scalars (no array -> no scratch risk).
    for (int g2 = 0; g2 < 2; g2++) {
        int s0 = wid * 16 + g2 * 8;
        f2 h00 = {0.f, 0.f}, h01 = {0.f, 0.f};
        f2 h10 = {0.f, 0.f}, h11 = {0.f, 0.f};
        f2 h20 = {0.f, 0.f}, h21 = {0.f, 0.f};
        f2 h30 = {0.f, 0.f}, h31 = {0.f, 0.f};
        f2 h40 = {0.f, 0.f}, h41 = {0.f, 0.f};
        f2 h50 = {0.f, 0.f}, h51 = {0.f, 0.f};
        f2 h60 = {0.f, 0.f}, h61 = {0.f, 0.f};
        f2 h70 = {0.f, 0.f}, h71 = {0.f, 0.f};
#pragma unroll 8
        for (int c = 0; c < DIM; c++) {
            float4 sva = *(const float4*)(sig + c * SIGS_B + s0);
            float4 svb = *(const float4*)(sig + c * SIGS_B + s0 + 4);
            float4 dv = *(const float4*)(Dn_g + c * NEMB + 4 * lane);
            f2 d0 = {dv.x, dv.y};
            f2 d1 = {dv.z, dv.w};
            h00 = __builtin_elementwise_fma((f2){sva.x, sva.x}, d0, h00);
            h01 = __builtin_elementwise_fma((f2){sva.x, sva.x}, d1, h01);
            h10 = __builtin_elementwise_fma((f2){sva.y, sva.y}, d0, h10);
            h11 = __builtin_elementwise_fma((f2){sva.y, sva.y}, d1, h11);
            h20 = __builtin_elementwise_fma((f2){sva.z, sva.z}, d0, h20);
            h21 = __builtin_elementwise_fma((f2){sva.z, sva.z}, d1, h21);
            h30 = __builtin_elementwise_fma((f2){sva.w, sva.w}, d0, h30);
            h31 = __builtin_elementwise_fma((f2){sva.w, sva.w}, d1, h31);
            h40 = __builtin_elementwise_fma((f2){svb.x, svb.x}, d0, h40);
            h41 = __builtin_elementwise_fma((f2){svb.x, svb.x}, d1, h41);
            h50 = __builtin_elementwise_fma((f2){svb.y, svb.y}, d0, h50);
            h51 = __builtin_elementwise_fma((f2){svb.y, svb.y}, d1, h51);
            h60 = __builtin_elementwise_fma((f2){svb.z, svb.z}, d0, h60);
            h61 = __builtin_elementwise_fma((f2){svb.z, svb.z}, d1, h61);
            h70 = __builtin_elementwise_fma((f2){svb.w, svb.w}, d0, h70);
            h71 = __builtin_elementwise_fma((f2){svb.w, svb.w}, d1, h71);
        }
        omp_quad4(h00, h01, h10, h11, h20, h21, h30, h31,
                  lane, qt, G, xsv, qi, s0);
        omp_quad4(h40, h41, h50, h51, h60, h61, h70, h71,
                  lane, qt, G, xsv, qi, s0 + 4);
    }
    __syncthreads();

    // thread-parallel mu-law quantize of all 256 coeffs (one per thread)
    {
        int jq = tid >> 6;
        int wq = tid & (SIGS_B - 1);
        xsv[jq * SIGS_B + wq] = quant_decode(xsv[jq * SIGS_B + wq]);
    }
    __syncthreads();

    // store phase: recon (einsum order: mul+add, k ascending, no fma),
    // gathers vectorized via DnT (DnT[i][c] == Dn[c][i], bit-identical).
    double lsum = 0.0;
    float* zqb = zq + ((size_t)b << 18) + pl0;
    {
#pragma clang fp contract(off)
        int w = tid & (SIGS_B - 1);
        int g = tid >> 6;
        float q0 = xsv[0 * SIGS_B + w], q1 = xsv[1 * SIGS_B + w];
        float q2 = xsv[2 * SIGS_B + w], q3 = xsv[3 * SIGS_B + w];
        int i0 = qi[0 * SIGS_B + w], i1 = qi[1 * SIGS_B + w];
        int i2 = qi[2 * SIGS_B + w], i3 = qi[3 * SIGS_B + w];
        const float* t0p = DnT_g + (i0 << 6) + (g << 4);
        const float* t1p = DnT_g + (i1 << 6) + (g << 4);
        const float* t2p = DnT_g + (i2 << 6) + (g << 4);
        const float* t3p = DnT_g + (i3 << 6) + (g << 4);
#pragma unroll
        for (int cb = 0; cb < 4; cb++) {
            float4 d0 = *(const float4*)(t0p + 4 * cb);
            float4 d1 = *(const float4*)(t1p + 4 * cb);
            float4 d2 = *(const float4*)(t2p + 4 * cb);
            float4 d3 = *(const float4*)(t3p + 4 * cb);
#pragma unroll
            for (int u = 0; u < 4; u++) {
                int c = (g << 4) + (cb << 2) + u;
                float e0 = (u == 0) ? d0.x : (u == 1) ? d0.y : (u == 2) ? d0.z : d0.w;
                float e1 = (u == 0) ? d1.x : (u == 1) ? d1.y : (u == 2) ? d1.z : d1.w;
                float e2 = (u == 0) ? d2.x : (u == 1) ? d2.y : (u == 2) ? d2.z : d2.w;
                float e3 = (u == 0) ? d3.x : (u == 1) ? d3.y : (u == 2) ? d3.z : d3.w;
                float p0 = q0 * e0;
                float p1 = q1 * e1;
                float p2 = q2 * e2;
                float p3 = q3 * e3;
                float r = p0 + p1;
                r = r + p2;
                r = r + p3;
                float zev = sig[c * SIGS_B + w];
                float d = r - zev;
                float zqv = zev + d;           // z_q = z_e + (recon - z_e)
                lsum += (double)d * (double)d;
                zqb[(size_t)c * 4096 + w] = zqv;
            }
        }
    }
#pragma unroll
    for (int off = 32; off > 0; off >>= 1) lsum += __shfl_xor(lsum, off);
    if (lane == 0) red[wid] = lsum;
    __syncthreads();
    if (tid == 0) {
        double t = 0.0;
#pragma unroll
        for (int i = 0; i < 4; i++) t += red[i];
        atomicAdd(loss_acc, t);
        __threadfence();
        unsigned int done = atomicAdd(ctr, 1u);
        if (done == GRID - 1) {
            double m = atomicAdd(loss_acc, 0.0) / 8388608.0;
            loss_out[0] = (float)(m + 0.25 * m);
        }
    }
}

extern "C" void kernel_launch(void* const* d_in, const int* in_sizes, int n_in,
                              void* d_out, int out_size, void* d_ws, size_t ws_size,
                              hipStream_t stream)
{
    const float* z = (const float*)d_in[0];
    const float* D = (const float*)d_in[1];
    float* out = (float*)d_out;
    char* ws = (char*)d_ws;
    double* loss_acc = (double*)ws;                       // 8 B
    unsigned int* ctr = (unsigned int*)(ws + 8);          // 4 B
    float* Dn = (float*)(ws + 256);                       // 64x256 f32
    float* G = (float*)(ws + 256 + 65536);                // 256x256 f32
    float* DnT = (float*)(ws + 256 + 65536 + 262144);     // 256x64 f32

    k_ng<<<NEMB, NEMB, 0, stream>>>(D, Dn, DnT, G, loss_acc, ctr);
    hipFuncSetAttribute(reinterpret_cast<const void*>(k_omp),
                        hipFuncAttributeMaxDynamicSharedMemorySize, LDS_BYTES);
    k_omp<<<GRID, THREADS, LDS_BYTES, stream>>>(z, Dn, DnT, G, loss_acc, ctr, out, out + 8388608);
    (void)in_sizes; (void)n_in; (void)out_size; (void)ws_size;
}